// Round 1
// baseline (330.210 us; speedup 1.0000x reference)
//
#include <hip/hip_runtime.h>

// Capsule dynamic routing, fully fused, fp32.
// x:[B,I,K]=32x2048x8, W:[J,I,D,K]=32x2048x16x8, out v:[B,J,D]=32x32x16.
// b-logits are linear in v (b_r = u_hat . sum_{r'<r} v_r'), so we only keep
// vsum[b,j,d]. Each routing iteration = one "pass" kernel (recomputes u_hat
// from W,x; softmax over j in-wave; accumulates s partials per i-chunk) +
// one reduce+squash kernel. Iteration 0 falls out for free (vsum=0 ->
// uniform softmax).

#define BATCH 32
#define ICAP  2048
#define KDIM  8
#define JCAP  32
#define DDIM  16
#define JD    512            // JCAP*DDIM
#define S_ELEMS 16384        // BATCH*JCAP*DDIM
#define WROW  132            // LDS row stride (128 floats + pad 4, keeps 16B align)
#define EPSQ  1e-7f

// ---------------------------------------------------------------------------
// Pass kernel: grid = NB blocks (i-chunks), 512 threads = 8 waves.
// Wave w handles b in {w, w+8, w+16, w+24}. Lane l -> j = l&31, dhalf = l>>5.
// Per i: stage W[:,i,:,:] (4096 floats) in LDS, hoist lane's 64 floats to
// regs, then for each of 4 b: u[8] (8 MAC each), t = u.vsum (shfl over d),
// softmax over j (shfl butterfly), sacc += c*u. Partials written per block.
// ---------------------------------------------------------------------------
__global__ __launch_bounds__(512, 2)
void caps_pass(const float* __restrict__ W, const float* __restrict__ x,
               const float* __restrict__ vsum, float* __restrict__ partials,
               int ichunk) {
    __shared__ float Wl[JCAP * WROW];          // 16.9 KB

    const int tid  = threadIdx.x;
    const int wave = tid >> 6;
    const int lane = tid & 63;
    const int j    = lane & 31;
    const int dh   = lane >> 5;                 // 0 or 1 (d half)
    const int i0   = blockIdx.x * ichunk;

    // cache vsum fragment + zero accumulators (4 b's per wave, 8 d's per lane)
    float vs[4][8];
    float sacc[4][8];
#pragma unroll
    for (int bb = 0; bb < 4; ++bb) {
        const int b = wave + 8 * bb;
        const float* vp = vsum + b * JD + j * DDIM + dh * 8;
        float4 a  = *reinterpret_cast<const float4*>(vp);
        float4 bq = *reinterpret_cast<const float4*>(vp + 4);
        vs[bb][0]=a.x; vs[bb][1]=a.y; vs[bb][2]=a.z; vs[bb][3]=a.w;
        vs[bb][4]=bq.x; vs[bb][5]=bq.y; vs[bb][6]=bq.z; vs[bb][7]=bq.w;
#pragma unroll
        for (int r = 0; r < 8; ++r) sacc[bb][r] = 0.f;
    }

    // W staging indices: float4 granularity. W[j,i,dk] -> f4 index
    // jj*65536 + i*32 + c  (row = 128 floats = 32 f4 chunks).
    const float4* Wv = reinterpret_cast<const float4*>(W);
    const int jj0 = tid >> 5, c0 = tid & 31;          // f4 #tid
    const int jj1 = (tid + 512) >> 5;                 // f4 #(tid+512), same c
    float4 pf0 = Wv[jj0 * 65536 + i0 * 32 + c0];
    float4 pf1 = Wv[jj1 * 65536 + i0 * 32 + c0];

    for (int ii = 0; ii < ichunk; ++ii) {
        const int i = i0 + ii;
        __syncthreads();                               // LDS free to overwrite
        *reinterpret_cast<float4*>(&Wl[jj0 * WROW + c0 * 4]) = pf0;
        *reinterpret_cast<float4*>(&Wl[jj1 * WROW + c0 * 4]) = pf1;
        __syncthreads();
        if (ii + 1 < ichunk) {                         // prefetch next i
            pf0 = Wv[jj0 * 65536 + (i + 1) * 32 + c0];
            pf1 = Wv[jj1 * 65536 + (i + 1) * 32 + c0];
        }

        // hoist this lane's W slice: dk = dh*64 + r*8 + k  (64 floats)
        float wreg[64];
        const float* wrow = &Wl[j * WROW + dh * 64];
#pragma unroll
        for (int r = 0; r < 8; ++r) {
            float4 a  = *reinterpret_cast<const float4*>(wrow + r * 8);
            float4 bq = *reinterpret_cast<const float4*>(wrow + r * 8 + 4);
            wreg[r*8+0]=a.x;  wreg[r*8+1]=a.y;  wreg[r*8+2]=a.z;  wreg[r*8+3]=a.w;
            wreg[r*8+4]=bq.x; wreg[r*8+5]=bq.y; wreg[r*8+6]=bq.z; wreg[r*8+7]=bq.w;
        }

#pragma unroll
        for (int bb = 0; bb < 4; ++bb) {
            const int b = wave + 8 * bb;
            const float* xp = x + (size_t)b * ICAP * KDIM + (size_t)i * KDIM;
            float4 xa = *reinterpret_cast<const float4*>(xp);
            float4 xb = *reinterpret_cast<const float4*>(xp + 4);
            const float xv[8] = {xa.x, xa.y, xa.z, xa.w, xb.x, xb.y, xb.z, xb.w};

            float u[8];
            float tpart = 0.f;
#pragma unroll
            for (int r = 0; r < 8; ++r) {
                float acc = 0.f;
#pragma unroll
                for (int k = 0; k < 8; ++k) acc = fmaf(wreg[r*8+k], xv[k], acc);
                u[r] = acc;
                tpart = fmaf(acc, vs[bb][r], tpart);
            }
            // full logit t[j]: combine the two d-halves (lane ^ 32)
            float t = tpart + __shfl_xor(tpart, 32);
            // softmax over j=32 (each j duplicated on lanes l and l^32)
            float m = t;
#pragma unroll
            for (int off = 1; off <= 16; off <<= 1)
                m = fmaxf(m, __shfl_xor(m, off));
            float e = __expf(t - m);
            float se = e;
#pragma unroll
            for (int off = 1; off <= 16; off <<= 1)
                se += __shfl_xor(se, off);
            const float c = e / se;
#pragma unroll
            for (int r = 0; r < 8; ++r) sacc[bb][r] = fmaf(c, u[r], sacc[bb][r]);
        }
    }

    // write block partials (each (b,j,d) exactly once per block)
    float* pout = partials + (size_t)blockIdx.x * S_ELEMS;
#pragma unroll
    for (int bb = 0; bb < 4; ++bb) {
        const int b = wave + 8 * bb;
        float* p = pout + b * JD + j * DDIM + dh * 8;
        float4 q0 = {sacc[bb][0], sacc[bb][1], sacc[bb][2], sacc[bb][3]};
        float4 q1 = {sacc[bb][4], sacc[bb][5], sacc[bb][6], sacc[bb][7]};
        *reinterpret_cast<float4*>(p)     = q0;
        *reinterpret_cast<float4*>(p + 4) = q1;
    }
}

// ---------------------------------------------------------------------------
// Reduce partials over NB chunks, squash over d (16-lane butterfly),
// update vsum, optionally emit v to out.
// ---------------------------------------------------------------------------
__global__ __launch_bounds__(512)
void caps_squash(const float* __restrict__ partials, int nb,
                 float* __restrict__ vsum, float* __restrict__ out) {
    const int e = blockIdx.x * 512 + threadIdx.x;
    float s = 0.f;
    for (int n = 0; n < nb; ++n)
        s += partials[(size_t)n * S_ELEMS + e];
    float n2 = s * s;
#pragma unroll
    for (int off = 1; off <= 8; off <<= 1)
        n2 += __shfl_xor(n2, off);
    const float scale = n2 / ((1.f + n2) * sqrtf(n2 + EPSQ));
    const float v = s * scale;
    vsum[e] += v;
    if (out) out[e] = v;
}

extern "C" void kernel_launch(void* const* d_in, const int* in_sizes, int n_in,
                              void* d_out, int out_size, void* d_ws, size_t ws_size,
                              hipStream_t stream) {
    const float* x = (const float*)d_in[0];   // [32,2048,8]
    const float* W = (const float*)d_in[1];   // [32,2048,16,8]
    float* out = (float*)d_out;               // [32,32,16]

    float* vsum     = (float*)d_ws;           // 64 KB
    float* partials = vsum + S_ELEMS;         // NB * 64 KB

    int NB = 256;                             // i-chunks (blocks per pass)
    while ((size_t)(NB + 1) * S_ELEMS * sizeof(float) > ws_size && NB > 8)
        NB >>= 1;
    const int ichunk = ICAP / NB;

    hipMemsetAsync(vsum, 0, S_ELEMS * sizeof(float), stream);

    for (int r = 0; r < 3; ++r) {
        caps_pass<<<NB, 512, 0, stream>>>(W, x, vsum, partials, ichunk);
        caps_squash<<<S_ELEMS / 512, 512, 0, stream>>>(
            partials, NB, vsum, (r == 2) ? out : nullptr);
    }
}